// Round 1
// baseline (640.151 us; speedup 1.0000x reference)
//
#include <hip/hip_runtime.h>

#define HDIM 16

// ---------------------------------------------------------------------------
// deg[dst] += 1 for every edge (self-loop handled as +1 in dinv_kernel)
// ---------------------------------------------------------------------------
__global__ void deg_kernel(const int* __restrict__ dst, float* __restrict__ deg, int E) {
    int i = blockIdx.x * blockDim.x + threadIdx.x;
    int stride = gridDim.x * blockDim.x;
    for (; i < E; i += stride)
        atomicAdd(&deg[dst[i]], 1.0f);
}

// dinv[i] = rsqrt(deg[i] + 1)   (+1 = self-loop; deg>0 always)
__global__ void dinv_kernel(float* __restrict__ deg, int n) {
    int i = blockIdx.x * blockDim.x + threadIdx.x;
    if (i < n)
        deg[i] = rsqrtf(deg[i] + 1.0f);
}

// ---------------------------------------------------------------------------
// Y[n,16] = X[n,K] @ W[K,16]   — W staged in LDS, one thread per row
// ---------------------------------------------------------------------------
template <int K>
__global__ void gemm_kernel(const float* __restrict__ X, const float* __restrict__ W,
                            float* __restrict__ Y, int n) {
    __shared__ float Wl[K * HDIM];
    for (int t = threadIdx.x; t < K * HDIM; t += blockDim.x)
        Wl[t] = W[t];
    __syncthreads();

    int row = blockIdx.x * blockDim.x + threadIdx.x;
    int stride = gridDim.x * blockDim.x;
    for (; row < n; row += stride) {
        float acc[HDIM];
#pragma unroll
        for (int j = 0; j < HDIM; ++j) acc[j] = 0.0f;
        const float* xr = X + (size_t)row * K;
#pragma unroll
        for (int k = 0; k < K; ++k) {
            float xv = xr[k];
#pragma unroll
            for (int j = 0; j < HDIM; ++j)
                acc[j] = fmaf(xv, Wl[k * HDIM + j], acc[j]);
        }
        float4* yo = (float4*)(Y + (size_t)row * HDIM);
        yo[0] = make_float4(acc[0], acc[1], acc[2], acc[3]);
        yo[1] = make_float4(acc[4], acc[5], acc[6], acc[7]);
        yo[2] = make_float4(acc[8], acc[9], acc[10], acc[11]);
        yo[3] = make_float4(acc[12], acc[13], acc[14], acc[15]);
    }
}

// ---------------------------------------------------------------------------
// agg[dst,:] += h[src,:] * dinv[src]*dinv[dst]  for every edge
// one thread per (edge, feature); 16 consecutive threads share an edge
// ---------------------------------------------------------------------------
__global__ void scatter_kernel(const int* __restrict__ src, const int* __restrict__ dst,
                               const float* __restrict__ h, const float* __restrict__ dinv,
                               float* __restrict__ agg, int E) {
    int total = E * HDIM;  // 51.2M < 2^31
    int idx = blockIdx.x * blockDim.x + threadIdx.x;
    int stride = gridDim.x * blockDim.x;
    for (; idx < total; idx += stride) {
        int e = idx >> 4;
        int j = idx & 15;
        int s = src[e];
        int d = dst[e];
        float norm = dinv[s] * dinv[d];
        atomicAdd(&agg[(size_t)d * HDIM + j], h[(size_t)s * HDIM + j] * norm);
    }
}

// ---------------------------------------------------------------------------
// out[i,j] = relu(agg[i,j] + h[i,j]*dinv[i]^2 + b[j])   (self-loop + bias)
// ---------------------------------------------------------------------------
__global__ void finish_kernel(const float* __restrict__ agg, const float* __restrict__ h,
                              const float* __restrict__ dinv, const float* __restrict__ b,
                              float* __restrict__ out, int n) {
    int total = n * HDIM;
    int idx = blockIdx.x * blockDim.x + threadIdx.x;
    int stride = gridDim.x * blockDim.x;
    for (; idx < total; idx += stride) {
        int i = idx >> 4;
        int j = idx & 15;
        float di = dinv[i];
        float v = agg[idx] + h[idx] * di * di + b[j];
        out[idx] = fmaxf(v, 0.0f);
    }
}

extern "C" void kernel_launch(void* const* d_in, const int* in_sizes, int n_in,
                              void* d_out, int out_size, void* d_ws, size_t ws_size,
                              hipStream_t stream) {
    const float* x  = (const float*)d_in[0];   // [n, 54]
    const int*   ei = (const int*)d_in[1];     // [2, E]
    const float* W1 = (const float*)d_in[2];   // [54, 16]
    const float* b1 = (const float*)d_in[3];   // [16]
    const float* W2 = (const float*)d_in[4];   // [16, 16]
    const float* b2 = (const float*)d_in[5];   // [16]
    float* out = (float*)d_out;

    const int E = in_sizes[1] / 2;             // 3,200,000
    const int n = in_sizes[0] / 54;            // 100,000
    const int* src = ei;
    const int* dst = ei + E;

    float* ws   = (float*)d_ws;
    float* dinv = ws;                          // n
    float* hA   = dinv + n;                    // 16n
    float* hB   = hA + (size_t)HDIM * n;       // 16n
    float* agg  = hB + (size_t)HDIM * n;       // 16n

    const int B = 256;

    // --- degree / normalization (shared by both layers) ---
    hipMemsetAsync(dinv, 0, (size_t)n * sizeof(float), stream);
    deg_kernel<<<2048, B, 0, stream>>>(dst, dinv, E);
    dinv_kernel<<<(n + B - 1) / B, B, 0, stream>>>(dinv, n);

    // --- layer 1 ---
    gemm_kernel<54><<<1024, B, 0, stream>>>(x, W1, hA, n);
    hipMemsetAsync(agg, 0, (size_t)HDIM * n * sizeof(float), stream);
    scatter_kernel<<<8192, B, 0, stream>>>(src, dst, hA, dinv, agg, E);
    finish_kernel<<<(n * HDIM + B - 1) / B, B, 0, stream>>>(agg, hA, dinv, b1, hB, n);

    // --- layer 2 ---
    gemm_kernel<16><<<1024, B, 0, stream>>>(hB, W2, hA, n);
    hipMemsetAsync(agg, 0, (size_t)HDIM * n * sizeof(float), stream);
    scatter_kernel<<<8192, B, 0, stream>>>(src, dst, hA, dinv, agg, E);
    finish_kernel<<<(n * HDIM + B - 1) / B, B, 0, stream>>>(agg, hA, dinv, b2, out, n);
}